// Round 1
// baseline (23.982 us; speedup 1.0000x reference)
//
#include <hip/hip_runtime.h>
#include <math.h>

// EPG simulation, one thread per pixel.
// State invariant: F+ = i*fp, F- = i*fm (pure imaginary), Z real.
// Per step (t = 0..31):
//   rotate:  rp = c2*fp + s2*fm - sa*z
//            rm = s2*fp + c2*fm + sa*z
//            zr = 0.5*sa*(fp-fm) + ca*z
//   echo_t = |rp[0]| * PD
//   shift+relax+conj (E2 scale & sign folded into A,B,C; E1 into D,Ez):
//   fp[0] = Rm[1]; fp[k] = Rp[k-1] (k>=1)
//   fm[k] = Rm[k+1] (k<=16); fm[17] = 0
//   z[k]  = Zn[k]; z[0] += 1-E1
// where Rp = A*fp + B*fm + C*z, Rm = B*fp + A*fm - C*z, Zn = D*(fp-fm) + Ez*z
//   A=-E2*c2, B=-E2*s2, C=E2*sa, D=E1*0.5*sa, Ez=E1*ca

#define NPULSES 32
#define KK 18    // kmax+1
#define KMAX 17

__global__ __launch_bounds__(256) void epg_kernel(
    const float* __restrict__ qm,   // (3, npix) flattened
    const int* __restrict__ tr_ptr, // scalar TR
    float* __restrict__ out,        // (npix, 32)
    int npix)
{
    int p = blockIdx.x * blockDim.x + threadIdx.x;
    if (p >= npix) return;

    float PD = qm[p];
    float T1 = fmaf(qm[npix + p], 5000.0f, 0.01f);
    float T2 = fmaf(qm[2 * npix + p], 1500.0f, 0.01f);
    float TR = (float)(*tr_ptr);
    float E1 = __expf(-TR / T1);
    float E2 = __expf(-TR / T2);

    // RF rotation constants, alpha = pi/4, phi = 0
    const float c2 = 0.8535533905932737f;   // cos^2(pi/8)
    const float s2 = 0.1464466094067263f;   // sin^2(pi/8)
    const float sa = 0.7071067811865476f;   // sin(pi/4)
    const float ca = 0.7071067811865476f;   // cos(pi/4)

    float A  = -E2 * c2;
    float B  = -E2 * s2;
    float C  =  E2 * sa;
    float D  =  E1 * 0.5f * sa;
    float Ez =  E1 * ca;
    float inj = 1.0f - E1;

    float fp[KK], fm[KK], z[KK];
    #pragma unroll
    for (int k = 0; k < KK; ++k) { fp[k] = 0.0f; fm[k] = 0.0f; z[k] = 0.0f; }
    z[0] = 1.0f;

    float* o = out + (size_t)p * NPULSES;

    #pragma unroll
    for (int t = 0; t < NPULSES; ++t) {
        // echo: UNSCALED rotated F+_0 magnitude (before E2/conj folding)
        float e = fmaf(c2, fp[0], fmaf(s2, fm[0], -sa * z[0]));
        o[t] = fabsf(e) * PD;

        float Rp[KK], Rm[KK], Zn[KK];
        #pragma unroll
        for (int k = 0; k < KK; ++k) {
            float pk = fp[k], mk = fm[k], zk = z[k];
            float Cz = C * zk;
            Rp[k] = fmaf(A, pk, fmaf(B, mk,  Cz));
            Rm[k] = fmaf(B, pk, fmaf(A, mk, -Cz));
            Zn[k] = fmaf(Ez, zk, D * (pk - mk));
        }

        // shift (incl. S[0:2,4]=1 quirk: both F+_0 and F-_0 get F-_1)
        fp[0] = Rm[1];
        #pragma unroll
        for (int k = KMAX; k >= 1; --k) fp[k] = Rp[k - 1];
        #pragma unroll
        for (int k = 0; k < KMAX; ++k) fm[k] = Rm[k + 1];
        fm[KMAX] = 0.0f;
        #pragma unroll
        for (int k = 0; k < KK; ++k) z[k] = Zn[k];
        z[0] += inj;
    }
}

extern "C" void kernel_launch(void* const* d_in, const int* in_sizes, int n_in,
                              void* d_out, int out_size, void* d_ws, size_t ws_size,
                              hipStream_t stream) {
    const float* qm = (const float*)d_in[0];
    const int* tr = (const int*)d_in[2];   // d_in[1] = n_pulses (compile-time 32)
    float* out = (float*)d_out;
    int npix = in_sizes[0] / 3;

    int block = 256;
    int grid = (npix + block - 1) / block;
    epg_kernel<<<grid, block, 0, stream>>>(qm, tr, out, npix);
}

// Round 3
// 21.233 us; speedup vs baseline: 1.1294x; 1.1294x over previous
//
#include <hip/hip_runtime.h>
#include <math.h>
#include <utility>

// EPG simulation, one thread per pixel, fully register-resident.
// State invariant: F+ = i*fp, F- = i*fm (pure imaginary), Z real.
// Banded-state pruning: after t shifts only k <= min(t,KMAX) is populated,
// so bound all k loops by compile-time L (t is a template/integral constant
// via static_for -> guaranteed full unroll, all register indices static).
//
// Per step:
//   echo_t = |c2*fp0 + s2*fm0 - sa*z0|      (PD pre-folded into state)
//   Rp = A*fp + B*fm + C*z
//   Rm = B*fp + A*fm - C*z
//   Zn = Ez*z + D*(fp - fm)
//   shift: fp[k]=Rp[k-1] (k>=1), fp[0]=Rm[1]; fm[k]=Rm[k+1]; z=Zn; z[0]+=inj
// with A=-E2*c2, B=-E2*s2, C=E2*sa, D=E1*sa/2, Ez=E1*ca, inj=(1-E1)*PD.

#define NPULSES 32
#define KK 18    // kmax+1
#define KMAX 17

template <typename F, int... Ts>
__device__ __forceinline__ void static_for(F&& f, std::integer_sequence<int, Ts...>) {
    (f(std::integral_constant<int, Ts>{}), ...);
}

__global__ __launch_bounds__(256) void epg_kernel(
    const float* __restrict__ qm,   // (3, npix) flattened
    const int* __restrict__ tr_ptr, // scalar TR
    float* __restrict__ out,        // (npix, 32)
    int npix)
{
    int p = blockIdx.x * blockDim.x + threadIdx.x;
    if (p >= npix) return;

    float PD = qm[p];
    float T1 = fmaf(qm[npix + p], 5000.0f, 0.01f);
    float T2 = fmaf(qm[2 * npix + p], 1500.0f, 0.01f);
    float TR = (float)(*tr_ptr);
    float E1 = __expf(-TR / T1);
    float E2 = __expf(-TR / T2);

    // RF rotation constants, alpha = pi/4, phi = 0
    const float c2 = 0.8535533905932737f;   // cos^2(pi/8)
    const float s2 = 0.1464466094067263f;   // sin^2(pi/8)
    const float sa = 0.7071067811865476f;   // sin(pi/4) == cos(pi/4)

    float A  = -E2 * c2;
    float B  = -E2 * s2;
    float C  =  E2 * sa;
    float D  =  E1 * 0.5f * sa;
    float Ez =  E1 * sa;                    // E1 * cos(alpha), ca == sa
    float inj = (1.0f - E1) * PD;           // PD folded into state scale

    float fp[KK], fm[KK], z[KK];
    #pragma unroll
    for (int k = 0; k < KK; ++k) { fp[k] = 0.0f; fm[k] = 0.0f; z[k] = 0.0f; }
    z[0] = PD;

    float* o = out + (size_t)p * NPULSES;

    static_for([&](auto tc) {
        constexpr int t = decltype(tc)::value;
        constexpr int L = (t < KMAX) ? t : KMAX;   // highest populated k

        // echo: unscaled rotated F+_0 magnitude (E2/conj not yet applied)
        float e = fmaf(c2, fp[0], fmaf(s2, fm[0], -sa * z[0]));
        o[t] = fabsf(e);

        float Rp[L + 1], Rm[L + 1], Zn[L + 1];
        #pragma unroll
        for (int k = 0; k <= L; ++k) {
            float pk = fp[k], mk = fm[k], zk = z[k];
            float Cz = C * zk;
            Rp[k] = fmaf(A, pk, fmaf(B, mk,  Cz));
            Rm[k] = fmaf(B, pk, fmaf(A, mk, -Cz));
            Zn[k] = fmaf(Ez, zk, D * (pk - mk));
        }

        // shift (incl. S[0:2,4]=1 quirk: F+_0 and F-_0 both get F-_1)
        constexpr int H = (L + 1 < KMAX) ? (L + 1) : KMAX;
        #pragma unroll
        for (int k = H; k >= 1; --k) fp[k] = Rp[k - 1];
        if constexpr (L >= 1) { fp[0] = Rm[1]; } else { fp[0] = 0.0f; }
        #pragma unroll
        for (int k = 0; k < L; ++k) fm[k] = Rm[k + 1];
        fm[L] = 0.0f;   // shifted in from (zero) k = L+1
        #pragma unroll
        for (int k = 0; k <= L; ++k) z[k] = Zn[k];
        z[0] += inj;
    }, std::make_integer_sequence<int, NPULSES>{});
}

extern "C" void kernel_launch(void* const* d_in, const int* in_sizes, int n_in,
                              void* d_out, int out_size, void* d_ws, size_t ws_size,
                              hipStream_t stream) {
    const float* qm = (const float*)d_in[0];
    const int* tr = (const int*)d_in[2];   // d_in[1] = n_pulses (compile-time 32)
    float* out = (float*)d_out;
    int npix = in_sizes[0] / 3;

    int block = 256;
    int grid = (npix + block - 1) / block;
    epg_kernel<<<grid, block, 0, stream>>>(qm, tr, out, npix);
}

// Round 4
// 20.431 us; speedup vs baseline: 1.1738x; 1.0393x over previous
//
#include <hip/hip_runtime.h>
#include <math.h>
#include <utility>

// EPG simulation, one thread per pixel, fully register-resident.
// State invariant: F+ = i*fp, F- = i*fm (pure imaginary), Z real.
//
// Double-sided band pruning:
//   forward:  after t shifts only k <= min(t, KMAX) is populated
//   backward: slot k entering step t can only influence echoes t' >= t+k
//             (inter-slot influence moves at most +-1 per step, echoes read
//             slot 0 only), so k > 31-t is dead.
//   rotation band A(t) = min(t, KMAX, 31-t); next-state band B = A(t+1).
// All loop bounds compile-time via static_for -> registers, no spills from
// dynamic indexing.
//
// Per step:
//   echo_t = |c2*fp0 + s2*fm0 - sa*z0|      (PD pre-folded into state)
//   Rp = A*fp + B*fm + C*z
//   Rm = B*fp + A*fm - C*z
//   Zn = Ez*z + D*(fp - fm)
//   shift: fp[k]=Rp[k-1] (k>=1), fp[0]=Rm[1]; fm[k]=Rm[k+1]; z=Zn; z[0]+=inj
// with A=-E2*c2, B=-E2*s2, C=E2*sa, D=E1*sa/2, Ez=E1*ca, inj=(1-E1)*PD.
//
// Echoes buffered in a 4-register ring, stored as global_store_dwordx4 every
// 4th step (8 stores instead of 32 -> 4x fewer scattered line-transactions).

#define NPULSES 32
#define KK 18    // kmax+1
#define KMAX 17

__host__ __device__ constexpr int cmin3(int a, int b, int c) {
    int m = a < b ? a : b; return m < c ? m : c;
}

template <typename F, int... Ts>
__device__ __forceinline__ void static_for(F&& f, std::integer_sequence<int, Ts...>) {
    (f(std::integral_constant<int, Ts>{}), ...);
}

__global__ __launch_bounds__(256) void epg_kernel(
    const float* __restrict__ qm,   // (3, npix) flattened
    const int* __restrict__ tr_ptr, // scalar TR
    float* __restrict__ out,        // (npix, 32)
    int npix)
{
    int p = blockIdx.x * blockDim.x + threadIdx.x;
    if (p >= npix) return;

    float PD = qm[p];
    float T1 = fmaf(qm[npix + p], 5000.0f, 0.01f);
    float T2 = fmaf(qm[2 * npix + p], 1500.0f, 0.01f);
    float TR = (float)(*tr_ptr);
    float E1 = __expf(-TR / T1);
    float E2 = __expf(-TR / T2);

    // RF rotation constants, alpha = pi/4, phi = 0
    const float c2 = 0.8535533905932737f;   // cos^2(pi/8)
    const float s2 = 0.1464466094067263f;   // sin^2(pi/8)
    const float sa = 0.7071067811865476f;   // sin(pi/4) == cos(pi/4)

    float Aa = -E2 * c2;
    float Bb = -E2 * s2;
    float C  =  E2 * sa;
    float D  =  E1 * 0.5f * sa;
    float Ez =  E1 * sa;                    // E1 * cos(alpha), ca == sa
    float inj = (1.0f - E1) * PD;           // PD folded into state scale

    float fp[KK], fm[KK], z[KK];
    #pragma unroll
    for (int k = 0; k < KK; ++k) { fp[k] = 0.0f; fm[k] = 0.0f; z[k] = 0.0f; }
    z[0] = PD;

    float4* o4 = (float4*)(out + (size_t)p * NPULSES);
    float ebuf[4];

    static_for([&](auto tc) {
        constexpr int t = decltype(tc)::value;
        constexpr int A = cmin3(t, KMAX, (NPULSES - 1) - t);   // rotation band

        // echo: unscaled rotated F+_0 magnitude (E2/conj not yet applied)
        float e = fmaf(c2, fp[0], fmaf(s2, fm[0], -sa * z[0]));
        ebuf[t & 3] = fabsf(e);
        if constexpr ((t & 3) == 3) {
            o4[t >> 2] = make_float4(ebuf[0], ebuf[1], ebuf[2], ebuf[3]);
        }

        if constexpr (t < NPULSES - 1) {
            constexpr int B = cmin3(t + 1, KMAX, (NPULSES - 2) - t); // next band

            // zero-top-padded temporaries: index A+1 is a genuine zero slot
            float Rp[A + 2], Rm[A + 2], Zn[A + 2];
            Rm[A + 1] = 0.0f; Zn[A + 1] = 0.0f;
            #pragma unroll
            for (int k = 0; k <= A; ++k) {
                float pk = fp[k], mk = fm[k], zk = z[k];
                float Cz = C * zk;
                Rp[k] = fmaf(Aa, pk, fmaf(Bb, mk,  Cz));
                Rm[k] = fmaf(Bb, pk, fmaf(Aa, mk, -Cz));
                Zn[k] = fmaf(Ez, zk, D * (pk - mk));
            }

            // shift into next-state band (S[0:2,4]=1 quirk: fp[0],fm[0] <- F-_1)
            #pragma unroll
            for (int k = B; k >= 1; --k) fp[k] = Rp[k - 1];
            fp[0] = Rm[1];                       // A==0 -> zero-top slot
            #pragma unroll
            for (int k = 0; k <= B; ++k) fm[k] = (k <= A) ? Rm[k + 1] : 0.0f;
            #pragma unroll
            for (int k = 0; k <= B; ++k) z[k] = Zn[k];   // B <= A+1, in-bounds
            z[0] += inj;
        }
    }, std::make_integer_sequence<int, NPULSES>{});
}

extern "C" void kernel_launch(void* const* d_in, const int* in_sizes, int n_in,
                              void* d_out, int out_size, void* d_ws, size_t ws_size,
                              hipStream_t stream) {
    const float* qm = (const float*)d_in[0];
    const int* tr = (const int*)d_in[2];   // d_in[1] = n_pulses (compile-time 32)
    float* out = (float*)d_out;
    int npix = in_sizes[0] / 3;

    int block = 256;
    int grid = (npix + block - 1) / block;
    epg_kernel<<<grid, block, 0, stream>>>(qm, tr, out, npix);
}